// Round 15
// baseline (106.364 us; speedup 1.0000x reference)
//
#include <hip/hip_runtime.h>

// Problem constants (from reference)
#define NN 4096
#define CC 128
#define II 9
#define DD 9
#define EE 10
#define PP3 23
#define PP2 5
#define PP1 3
// symmetric monomial counts over 9 vars
#define F3 165   // i<=j<=k
#define F2 45    // i<=j
#define F1 9
#define FTOT (F3 + F2 + F1)  // 219
#define FPAD 224             // padded K (14 x 16)
#define NKT14 14             // K-tiles of 16 (32x32x16 MFMA)

// workspace layout (bytes)
#define SU3_ELEMS (F3 * PP3 * DD)              // 34155 floats
#define SU2_ELEMS (F2 * PP2 * DD)              // 2025 floats
#define SU3_OFF 0
#define SU2_OFF (SU3_OFF + SU3_ELEMS * 4)
#define CUR_OFF (SU2_OFF + SU2_ELEMS * 4)
#define LIST_OFF (CUR_OFF + 64)                // 16 ints + pad
#define WG16_OFF (LIST_OFF + NN * EE * 4)      // f16 W images: E*C*9*224*2 = 5.2 MB

#define CPB 4      // channels per block (1 per wave)
#define TS 16      // tile-stride (grid z) — round-15: 5120 blocks, 5 waves/SIMD

typedef _Float16 f16x8 __attribute__((ext_vector_type(8)));
typedef __fp16 fp16x2 __attribute__((ext_vector_type(2)));   // cvt_pkrtz return type
typedef float f32x16 __attribute__((ext_vector_type(16)));

static __device__ __forceinline__ unsigned pkrtz(float a, float b) {
    fp16x2 h = __builtin_amdgcn_cvt_pkrtz(a, b);
    return __builtin_bit_cast(unsigned, h);
}

static __device__ __forceinline__ unsigned short h16(float a) {
    _Float16 ha = (_Float16)a;
    return __builtin_bit_cast(unsigned short, ha);
}

// Fused: symmetrize u3/u2 (one thread per (t,p,d) output element) + zero
// the bucket cursors (16 spare threads).
__global__ void sym_u_zero_kernel(const float* __restrict__ u3,
                                  const float* __restrict__ u2,
                                  float* __restrict__ su3,
                                  float* __restrict__ su2,
                                  int* __restrict__ cursors) {
    int gid = blockIdx.x * blockDim.x + threadIdx.x;
    if (gid < F3 * PP3 * 9) {
        const int t = gid / (PP3 * 9);
        const int rr = gid % (PP3 * 9);
        const int p = rr / 9;
        const int d = rr % 9;
        int I0 = 0, J0 = 0, K0 = 0;
        {
            int rem = t;
            bool found = false;
            for (int i = 0; i < 9 && !found; i++)
                for (int j = i; j < 9 && !found; j++) {
                    int cnt = 9 - j;
                    if (rem < cnt) { I0 = i; J0 = j; K0 = j + rem; found = true; }
                    else rem -= cnt;
                }
        }
        int a[3] = {I0, J0, K0};
        const int ord[6][3] = {{0,1,2},{0,2,1},{1,0,2},{1,2,0},{2,0,1},{2,1,0}};
        int codes[6];
        int np = 0;
        float s = 0.f;
        for (int q = 0; q < 6; q++) {
            int ii = a[ord[q][0]], jj = a[ord[q][1]], kk = a[ord[q][2]];
            int code = (ii * 9 + jj) * 9 + kk;
            bool seen = false;
            for (int r = 0; r < np; r++) if (codes[r] == code) seen = true;
            if (!seen) {
                codes[np++] = code;
                s += u3[(((((d * 9 + ii) * 9 + jj) * 9 + kk)) * PP3) + p];
            }
        }
        su3[(t * PP3 + p) * 9 + d] = s;
    } else if (gid < F3 * PP3 * 9 + F2 * PP2 * 9) {
        const int g2 = gid - F3 * PP3 * 9;
        const int t = g2 / (PP2 * 9);
        const int rr = g2 % (PP2 * 9);
        const int p = rr / 9;
        const int d = rr % 9;
        int I0 = 0, J0 = 0;
        {
            int rem = t;
            bool found = false;
            for (int i = 0; i < 9 && !found; i++) {
                int cnt = 9 - i;
                if (rem < cnt) { I0 = i; J0 = i + rem; found = true; }
                else rem -= cnt;
            }
        }
        float s = u2[(((d * 9 + I0) * 9 + J0) * PP2) + p];
        if (I0 != J0) s += u2[(((d * 9 + J0) * 9 + I0) * PP2) + p];
        su2[(t * PP2 + p) * 9 + d] = s;
    } else if (gid < F3 * PP3 * 9 + F2 * PP2 * 9 + 16) {
        cursors[gid - (F3 * PP3 * 9 + F2 * PP2 * 9)] = 0;
    }
}

// Atomic append bucketing. List ORDER is nondeterministic, but each node's
// result is a fixed-order dot product independent of its list slot, so
// d_out is bit-deterministic.
__global__ void bucket_kernel(const int* __restrict__ indices,
                              int* __restrict__ cursors,
                              int* __restrict__ lists) {
    int b = blockIdx.x * blockDim.x + threadIdx.x;
    if (b < NN) {
        int e = indices[b];
        int slot = atomicAdd(&cursors[e], 1);
        lists[e * NN + slot] = b;
    }
}

// Precompute per-(e,c) f16 weight image, layout [d (9 rows)][f (224, K)].
__global__ __launch_bounds__(256) void wprep16_kernel(
    const float* __restrict__ su3,
    const float* __restrict__ su2,
    const float* __restrict__ u1,
    const float* __restrict__ w3,
    const float* __restrict__ w2,
    const float* __restrict__ w1,
    unsigned* __restrict__ Wg16)
{
    const int c = blockIdx.x;
    const int e = blockIdx.y;
    const int tid = threadIdx.x;

    __shared__ unsigned short sImg[9 * FPAD];   // 4 KB f16 image [d][f]
    unsigned* sImgW = reinterpret_cast<unsigned*>(sImg);
    for (int q = tid; q < 9 * FPAD / 2; q += 256) sImgW[q] = 0u;
    __syncthreads();

    if (tid < FTOT) {
        float acc[9];
        #pragma unroll
        for (int d = 0; d < 9; d++) acc[d] = 0.f;

        if (tid < F3) {
            const float* sp = su3 + (size_t)tid * PP3 * 9;
            #pragma unroll
            for (int p = 0; p < PP3; p++) {
                const float wv = w3[(e * PP3 + p) * CC + c];     // uniform -> SGPR
                const float4 a = *reinterpret_cast<const float4*>(sp + p * 9);
                const float4 b = *reinterpret_cast<const float4*>(sp + p * 9 + 4);
                const float g = sp[p * 9 + 8];
                acc[0] += wv * a.x; acc[1] += wv * a.y; acc[2] += wv * a.z; acc[3] += wv * a.w;
                acc[4] += wv * b.x; acc[5] += wv * b.y; acc[6] += wv * b.z; acc[7] += wv * b.w;
                acc[8] += wv * g;
            }
        } else if (tid < F3 + F2) {
            const float* sp = su2 + (size_t)(tid - F3) * PP2 * 9;
            #pragma unroll
            for (int p = 0; p < PP2; p++) {
                const float wv = w2[(e * PP2 + p) * CC + c];
                const float4 a = *reinterpret_cast<const float4*>(sp + p * 9);
                const float4 b = *reinterpret_cast<const float4*>(sp + p * 9 + 4);
                const float g = sp[p * 9 + 8];
                acc[0] += wv * a.x; acc[1] += wv * a.y; acc[2] += wv * a.z; acc[3] += wv * a.w;
                acc[4] += wv * b.x; acc[5] += wv * b.y; acc[6] += wv * b.z; acc[7] += wv * b.w;
                acc[8] += wv * g;
            }
        } else {
            const int i = tid - F3 - F2;
            #pragma unroll
            for (int p = 0; p < PP1; p++) {
                const float wv = w1[(e * PP1 + p) * CC + c];
                #pragma unroll
                for (int d = 0; d < 9; d++)
                    acc[d] += wv * u1[(d * 9 + i) * PP1 + p];
            }
        }
        #pragma unroll
        for (int d = 0; d < 9; d++)
            sImg[d * FPAD + tid] = h16(acc[d]);
    }
    __syncthreads();

    unsigned* dst = Wg16 + (size_t)(e * CC + c) * (9 * FPAD / 2);
    for (int q = tid; q < 9 * FPAD / 2; q += 256) dst[q] = sImgW[q];
}

// Main kernel, round 15: identical body to round 14 (32x32x16 MFMA,
// barrier/LDS-free, shfl-scatter, 2-deep pipeline); TS=16 doubles the grid
// to 5120 blocks (5 waves/SIMD) — round-14 diagnosis: occupancy was
// GRID-limited (2.5 waves/SIMD), not resource-limited (VGPR=64).
__global__ __launch_bounds__(256, 4) void symcon_reg32_kernel(
    const float* __restrict__ x,
    const unsigned short* __restrict__ Wg16,
    const int* __restrict__ cursors,
    const int* __restrict__ lists,
    float* __restrict__ out)
{
    const int e = blockIdx.y;
    const int lane = threadIdx.x & 63;
    const int wid = threadIdx.x >> 6;
    const int c = blockIdx.x * CPB + wid;
    const int r = lane & 31;       // node row within tile; also B col (= d)
    const int g = lane >> 5;       // k-half
    const bool isg1 = (g == 1);

    const int cnt = cursors[e];
    const int ntiles = (cnt + 31) >> 5;
    if ((int)blockIdx.z >= ntiles) return;   // early exit before bfrag load

    // B fragments: lane holds B[k = t*16 + g*8 + j][col = r], zeros for col>=9
    f16x8 bfrag[NKT14];
    {
        const unsigned short* wp = Wg16 + (size_t)(e * CC + c) * (9 * FPAD);
        #pragma unroll
        for (int t = 0; t < NKT14; t++) {
            f16x8 v = {0, 0, 0, 0, 0, 0, 0, 0};
            if (r < 9)
                v = *reinterpret_cast<const f16x8*>(wp + r * FPAD + t * 16 + g * 8);
            bfrag[t] = v;
        }
    }

    const int* lbase = lists + e * NN;
    float* outc = out + (size_t)c * DD;

    int T = blockIdx.z;
    int nb_cur, nb_next;
    float xv[9];
    {
        const int n = T * 32 + r;
        const bool valid = (n < cnt);
        nb_cur = valid ? lbase[n] : 0;
        const float* xr = x + ((size_t)nb_cur * CC + c) * II;
        #pragma unroll
        for (int q = 0; q < 9; q++) xv[q] = valid ? xr[q] : 0.f;
    }
    {
        const int n = (T + TS) * 32 + r;
        const bool valid = (T + TS < ntiles) && (n < cnt);
        nb_next = valid ? lbase[n] : 0;
    }

    while (T < ntiles) {
        // ---- independent prefetches: x row for T+TS (id already in hand),
        //      id for T+2*TS ----
        float xn[9];
        {
            const int n = (T + TS) * 32 + r;
            const bool valid = (T + TS < ntiles) && (n < cnt);
            const float* xr = x + ((size_t)nb_next * CC + c) * II;
            #pragma unroll
            for (int q = 0; q < 9; q++) xn[q] = valid ? xr[q] : 0.f;
        }
        int nb_next2;
        {
            const int n = (T + 2 * TS) * 32 + r;
            const bool valid = (T + 2 * TS < ntiles) && (n < cnt);
            nb_next2 = valid ? lbase[n] : 0;
        }

        // ---- monomial stream with interleaved MFMA ----
        f32x16 acc = {0.f, 0.f, 0.f, 0.f, 0.f, 0.f, 0.f, 0.f,
                      0.f, 0.f, 0.f, 0.f, 0.f, 0.f, 0.f, 0.f};
        unsigned au[4];
        {
            float pend = 0.f;
            int F = 0;
            // Pair P = F>>1: K-tile t = P>>3, q = P&7, dword jd = q&3 — all
            // compile-time after unroll. q<4 writes unconditional (g1 lanes
            // overwritten by their q>=4 select). At q==7 fragment complete
            // -> MFMA.
#define EMITR(expr) { const float _m = (expr);                                \
            if (F & 1) { const unsigned _pk = pkrtz(pend, _m);                \
                const int _P = F >> 1; const int _t = _P >> 3;                \
                const int _q = _P & 7; const int _jd = _q & 3;                \
                if (_q < 4) au[_jd] = _pk;                                    \
                else        au[_jd] = isg1 ? _pk : au[_jd];                   \
                if (_q == 7) {                                                \
                    f16x8 af;                                                 \
                    unsigned* _ap = reinterpret_cast<unsigned*>(&af);         \
                    _ap[0] = au[0]; _ap[1] = au[1];                           \
                    _ap[2] = au[2]; _ap[3] = au[3];                           \
                    acc = __builtin_amdgcn_mfma_f32_32x32x16_f16(             \
                        af, bfrag[_t], acc, 0, 0, 0);                         \
                }                                                             \
            } else pend = _m; F++; }
            #pragma unroll
            for (int i = 0; i < 9; i++)
                #pragma unroll
                for (int j = i; j < 9; j++) {
                    const float xij = xv[i] * xv[j];
                    #pragma unroll
                    for (int k = j; k < 9; k++)
                        EMITR(xij * xv[k])
                }
            #pragma unroll
            for (int i = 0; i < 9; i++)
                #pragma unroll
                for (int j = i; j < 9; j++)
                    EMITR(xv[i] * xv[j])
            #pragma unroll
            for (int i = 0; i < 9; i++)
                EMITR(xv[i])
            #pragma unroll
            for (int z = 0; z < 5; z++)   // zero-pad f 219..223 (exactly 224)
                EMITR(0.f)
#undef EMITR
        }

        // ---- scatter D: col = r (= d), row = (reg&3) + 8*(reg>>2) + 4*g.
        // Node id for row comes from lane 'row' via shfl (all lanes
        // participate; store guarded afterwards). ----
        #pragma unroll
        for (int reg = 0; reg < 16; reg++) {
            const int row = (reg & 3) + 8 * (reg >> 2) + 4 * g;
            const int sb = __shfl(nb_cur, row);
            const int slot = T * 32 + row;
            if (r < 9 && slot < cnt)
                outc[(size_t)sb * (CC * DD) + r] = acc[reg];
        }

        #pragma unroll
        for (int q = 0; q < 9; q++) xv[q] = xn[q];
        nb_cur = nb_next;
        nb_next = nb_next2;
        T += TS;
    }
}

extern "C" void kernel_launch(void* const* d_in, const int* in_sizes, int n_in,
                              void* d_out, int out_size, void* d_ws, size_t ws_size,
                              hipStream_t stream) {
    const float* x   = (const float*)d_in[0];
    const int* indices = (const int*)d_in[1];
    const float* u3  = (const float*)d_in[2];
    const float* u2  = (const float*)d_in[3];
    const float* u1  = (const float*)d_in[4];
    const float* w3  = (const float*)d_in[5];
    const float* w2  = (const float*)d_in[6];
    const float* w1  = (const float*)d_in[7];
    float* out = (float*)d_out;

    char* ws = (char*)d_ws;
    float* su3 = (float*)(ws + SU3_OFF);
    float* su2 = (float*)(ws + SU2_OFF);
    int* cursors = (int*)(ws + CUR_OFF);
    int* lists = (int*)(ws + LIST_OFF);
    unsigned* Wg16 = (unsigned*)(ws + WG16_OFF);

    const int symn = F3 * PP3 * 9 + F2 * PP2 * 9 + 16;
    hipLaunchKernelGGL(sym_u_zero_kernel, dim3((symn + 255) / 256), dim3(256), 0, stream,
                       u3, u2, su3, su2, cursors);
    hipLaunchKernelGGL(bucket_kernel, dim3((NN + 255) / 256), dim3(256), 0, stream,
                       indices, cursors, lists);
    hipLaunchKernelGGL(wprep16_kernel, dim3(CC, EE), dim3(256), 0, stream,
                       su3, su2, u1, w3, w2, w1, Wg16);
    hipLaunchKernelGGL(symcon_reg32_kernel, dim3(CC / CPB, EE, TS), dim3(256), 0, stream,
                       x, (const unsigned short*)Wg16, cursors, lists, out);
}

// Round 16
// 99.364 us; speedup vs baseline: 1.0704x; 1.0704x over previous
//
#include <hip/hip_runtime.h>

// Problem constants (from reference)
#define NN 4096
#define CC 128
#define II 9
#define DD 9
#define EE 10
#define PP3 23
#define PP2 5
#define PP1 3
// symmetric monomial counts over 9 vars
#define F3 165   // i<=j<=k
#define F2 45    // i<=j
#define F1 9
#define FTOT (F3 + F2 + F1)  // 219
#define FPAD 224             // padded K (14 x 16)
#define NKT14 14             // K-tiles of 16 (32x32x16 MFMA)

// workspace layout (bytes)
#define SU3_ELEMS (F3 * PP3 * DD)              // 34155 floats
#define SU2_ELEMS (F2 * PP2 * DD)              // 2025 floats
#define SU3_OFF 0
#define SU2_OFF (SU3_OFF + SU3_ELEMS * 4)
#define CUR_OFF (SU2_OFF + SU2_ELEMS * 4)
#define LIST_OFF (CUR_OFF + 64)                // 16 ints + pad
#define WG16_OFF (LIST_OFF + NN * EE * 4)      // f16 W images: E*C*9*224*2 = 5.2 MB

#define CPB 4      // channels per block (1 per wave)
#define TS 8       // tile-stride (grid z) — round-16: back to r14's 2560 blocks

typedef _Float16 f16x8 __attribute__((ext_vector_type(8)));
typedef __fp16 fp16x2 __attribute__((ext_vector_type(2)));   // cvt_pkrtz return type
typedef float f32x16 __attribute__((ext_vector_type(16)));

static __device__ __forceinline__ unsigned pkrtz(float a, float b) {
    fp16x2 h = __builtin_amdgcn_cvt_pkrtz(a, b);
    return __builtin_bit_cast(unsigned, h);
}

static __device__ __forceinline__ unsigned short h16(float a) {
    _Float16 ha = (_Float16)a;
    return __builtin_bit_cast(unsigned short, ha);
}

// Fused: symmetrize u3/u2 (one thread per (t,p,d) output element) + zero
// the bucket cursors (16 spare threads).
__global__ void sym_u_zero_kernel(const float* __restrict__ u3,
                                  const float* __restrict__ u2,
                                  float* __restrict__ su3,
                                  float* __restrict__ su2,
                                  int* __restrict__ cursors) {
    int gid = blockIdx.x * blockDim.x + threadIdx.x;
    if (gid < F3 * PP3 * 9) {
        const int t = gid / (PP3 * 9);
        const int rr = gid % (PP3 * 9);
        const int p = rr / 9;
        const int d = rr % 9;
        int I0 = 0, J0 = 0, K0 = 0;
        {
            int rem = t;
            bool found = false;
            for (int i = 0; i < 9 && !found; i++)
                for (int j = i; j < 9 && !found; j++) {
                    int cnt = 9 - j;
                    if (rem < cnt) { I0 = i; J0 = j; K0 = j + rem; found = true; }
                    else rem -= cnt;
                }
        }
        int a[3] = {I0, J0, K0};
        const int ord[6][3] = {{0,1,2},{0,2,1},{1,0,2},{1,2,0},{2,0,1},{2,1,0}};
        int codes[6];
        int np = 0;
        float s = 0.f;
        for (int q = 0; q < 6; q++) {
            int ii = a[ord[q][0]], jj = a[ord[q][1]], kk = a[ord[q][2]];
            int code = (ii * 9 + jj) * 9 + kk;
            bool seen = false;
            for (int r = 0; r < np; r++) if (codes[r] == code) seen = true;
            if (!seen) {
                codes[np++] = code;
                s += u3[(((((d * 9 + ii) * 9 + jj) * 9 + kk)) * PP3) + p];
            }
        }
        su3[(t * PP3 + p) * 9 + d] = s;
    } else if (gid < F3 * PP3 * 9 + F2 * PP2 * 9) {
        const int g2 = gid - F3 * PP3 * 9;
        const int t = g2 / (PP2 * 9);
        const int rr = g2 % (PP2 * 9);
        const int p = rr / 9;
        const int d = rr % 9;
        int I0 = 0, J0 = 0;
        {
            int rem = t;
            bool found = false;
            for (int i = 0; i < 9 && !found; i++) {
                int cnt = 9 - i;
                if (rem < cnt) { I0 = i; J0 = i + rem; found = true; }
                else rem -= cnt;
            }
        }
        float s = u2[(((d * 9 + I0) * 9 + J0) * PP2) + p];
        if (I0 != J0) s += u2[(((d * 9 + J0) * 9 + I0) * PP2) + p];
        su2[(t * PP2 + p) * 9 + d] = s;
    } else if (gid < F3 * PP3 * 9 + F2 * PP2 * 9 + 16) {
        cursors[gid - (F3 * PP3 * 9 + F2 * PP2 * 9)] = 0;
    }
}

// Atomic append bucketing. List ORDER is nondeterministic, but each node's
// result is a fixed-order dot product independent of its list slot, so
// d_out is bit-deterministic.
__global__ void bucket_kernel(const int* __restrict__ indices,
                              int* __restrict__ cursors,
                              int* __restrict__ lists) {
    int b = blockIdx.x * blockDim.x + threadIdx.x;
    if (b < NN) {
        int e = indices[b];
        int slot = atomicAdd(&cursors[e], 1);
        lists[e * NN + slot] = b;
    }
}

// Precompute per-(e,c) f16 weight image, layout [d (9 rows)][f (224, K)].
__global__ __launch_bounds__(256) void wprep16_kernel(
    const float* __restrict__ su3,
    const float* __restrict__ su2,
    const float* __restrict__ u1,
    const float* __restrict__ w3,
    const float* __restrict__ w2,
    const float* __restrict__ w1,
    unsigned* __restrict__ Wg16)
{
    const int c = blockIdx.x;
    const int e = blockIdx.y;
    const int tid = threadIdx.x;

    __shared__ unsigned short sImg[9 * FPAD];   // 4 KB f16 image [d][f]
    unsigned* sImgW = reinterpret_cast<unsigned*>(sImg);
    for (int q = tid; q < 9 * FPAD / 2; q += 256) sImgW[q] = 0u;
    __syncthreads();

    if (tid < FTOT) {
        float acc[9];
        #pragma unroll
        for (int d = 0; d < 9; d++) acc[d] = 0.f;

        if (tid < F3) {
            const float* sp = su3 + (size_t)tid * PP3 * 9;
            #pragma unroll
            for (int p = 0; p < PP3; p++) {
                const float wv = w3[(e * PP3 + p) * CC + c];     // uniform -> SGPR
                const float4 a = *reinterpret_cast<const float4*>(sp + p * 9);
                const float4 b = *reinterpret_cast<const float4*>(sp + p * 9 + 4);
                const float g = sp[p * 9 + 8];
                acc[0] += wv * a.x; acc[1] += wv * a.y; acc[2] += wv * a.z; acc[3] += wv * a.w;
                acc[4] += wv * b.x; acc[5] += wv * b.y; acc[6] += wv * b.z; acc[7] += wv * b.w;
                acc[8] += wv * g;
            }
        } else if (tid < F3 + F2) {
            const float* sp = su2 + (size_t)(tid - F3) * PP2 * 9;
            #pragma unroll
            for (int p = 0; p < PP2; p++) {
                const float wv = w2[(e * PP2 + p) * CC + c];
                const float4 a = *reinterpret_cast<const float4*>(sp + p * 9);
                const float4 b = *reinterpret_cast<const float4*>(sp + p * 9 + 4);
                const float g = sp[p * 9 + 8];
                acc[0] += wv * a.x; acc[1] += wv * a.y; acc[2] += wv * a.z; acc[3] += wv * a.w;
                acc[4] += wv * b.x; acc[5] += wv * b.y; acc[6] += wv * b.z; acc[7] += wv * b.w;
                acc[8] += wv * g;
            }
        } else {
            const int i = tid - F3 - F2;
            #pragma unroll
            for (int p = 0; p < PP1; p++) {
                const float wv = w1[(e * PP1 + p) * CC + c];
                #pragma unroll
                for (int d = 0; d < 9; d++)
                    acc[d] += wv * u1[(d * 9 + i) * PP1 + p];
            }
        }
        #pragma unroll
        for (int d = 0; d < 9; d++)
            sImg[d * FPAD + tid] = h16(acc[d]);
    }
    __syncthreads();

    unsigned* dst = Wg16 + (size_t)(e * CC + c) * (9 * FPAD / 2);
    for (int q = tid; q < 9 * FPAD / 2; q += 256) dst[q] = sImgW[q];
}

// Main kernel, round 16: round-14 body (TS=8, 32x32x16 MFMA, shfl-free
// pipeline) + LDS-staged COALESCED output. Round-15 lesson: scattered 36B
// partial-line stores amplified WRITE 2.5-5.8x (109MB vs 19MB ideal) and the
// kernel went HBM-write-bound. Now the block's [32 node][4 ch][9 d] result
// tile is staged in LDS and written as 9 aligned float4 per node — each
// node's 144B contiguous, full-line writes.
__global__ __launch_bounds__(256, 4) void symcon_reg32_kernel(
    const float* __restrict__ x,
    const unsigned short* __restrict__ Wg16,
    const int* __restrict__ cursors,
    const int* __restrict__ lists,
    float* __restrict__ out)
{
    const int e = blockIdx.y;
    const int lane = threadIdx.x & 63;
    const int wid = threadIdx.x >> 6;
    const int c = blockIdx.x * CPB + wid;
    const int r = lane & 31;       // node row within tile; also B col (= d)
    const int g = lane >> 5;       // k-half
    const bool isg1 = (g == 1);

    const int cnt = cursors[e];
    const int ntiles = (cnt + 31) >> 5;
    if ((int)blockIdx.z >= ntiles) return;   // uniform early exit

    __shared__ __align__(16) float sOut[32 * 40];   // [node][40] dword rows
    __shared__ int sNid[32];

    // B fragments: lane holds B[k = t*16 + g*8 + j][col = r], zeros for col>=9
    f16x8 bfrag[NKT14];
    {
        const unsigned short* wp = Wg16 + (size_t)(e * CC + c) * (9 * FPAD);
        #pragma unroll
        for (int t = 0; t < NKT14; t++) {
            f16x8 v = {0, 0, 0, 0, 0, 0, 0, 0};
            if (r < 9)
                v = *reinterpret_cast<const f16x8*>(wp + r * FPAD + t * 16 + g * 8);
            bfrag[t] = v;
        }
    }

    const int* lbase = lists + e * NN;

    int T = blockIdx.z;
    int nb_cur, nb_next;
    float xv[9];
    {
        const int n = T * 32 + r;
        const bool valid = (n < cnt);
        nb_cur = valid ? lbase[n] : 0;
        const float* xr = x + ((size_t)nb_cur * CC + c) * II;
        #pragma unroll
        for (int q = 0; q < 9; q++) xv[q] = valid ? xr[q] : 0.f;
    }
    {
        const int n = (T + TS) * 32 + r;
        const bool valid = (T + TS < ntiles) && (n < cnt);
        nb_next = valid ? lbase[n] : 0;
    }

    while (T < ntiles) {
        // node ids for this tile (threads 0..31 hold r=0..31, same for all waves)
        if (threadIdx.x < 32) sNid[threadIdx.x] = nb_cur;

        // ---- independent prefetches: x row for T+TS (id already in hand),
        //      id for T+2*TS ----
        float xn[9];
        {
            const int n = (T + TS) * 32 + r;
            const bool valid = (T + TS < ntiles) && (n < cnt);
            const float* xr = x + ((size_t)nb_next * CC + c) * II;
            #pragma unroll
            for (int q = 0; q < 9; q++) xn[q] = valid ? xr[q] : 0.f;
        }
        int nb_next2;
        {
            const int n = (T + 2 * TS) * 32 + r;
            const bool valid = (T + 2 * TS < ntiles) && (n < cnt);
            nb_next2 = valid ? lbase[n] : 0;
        }

        // ---- monomial stream with interleaved MFMA ----
        f32x16 acc = {0.f, 0.f, 0.f, 0.f, 0.f, 0.f, 0.f, 0.f,
                      0.f, 0.f, 0.f, 0.f, 0.f, 0.f, 0.f, 0.f};
        unsigned au[4];
        {
            float pend = 0.f;
            int F = 0;
            // Pair P = F>>1: K-tile t = P>>3, q = P&7, dword jd = q&3 — all
            // compile-time after unroll. q<4 writes unconditional (g1 lanes
            // overwritten by their q>=4 select). At q==7 fragment complete
            // -> MFMA.
#define EMITR(expr) { const float _m = (expr);                                \
            if (F & 1) { const unsigned _pk = pkrtz(pend, _m);                \
                const int _P = F >> 1; const int _t = _P >> 3;                \
                const int _q = _P & 7; const int _jd = _q & 3;                \
                if (_q < 4) au[_jd] = _pk;                                    \
                else        au[_jd] = isg1 ? _pk : au[_jd];                   \
                if (_q == 7) {                                                \
                    f16x8 af;                                                 \
                    unsigned* _ap = reinterpret_cast<unsigned*>(&af);         \
                    _ap[0] = au[0]; _ap[1] = au[1];                           \
                    _ap[2] = au[2]; _ap[3] = au[3];                           \
                    acc = __builtin_amdgcn_mfma_f32_32x32x16_f16(             \
                        af, bfrag[_t], acc, 0, 0, 0);                         \
                }                                                             \
            } else pend = _m; F++; }
            #pragma unroll
            for (int i = 0; i < 9; i++)
                #pragma unroll
                for (int j = i; j < 9; j++) {
                    const float xij = xv[i] * xv[j];
                    #pragma unroll
                    for (int k = j; k < 9; k++)
                        EMITR(xij * xv[k])
                }
            #pragma unroll
            for (int i = 0; i < 9; i++)
                #pragma unroll
                for (int j = i; j < 9; j++)
                    EMITR(xv[i] * xv[j])
            #pragma unroll
            for (int i = 0; i < 9; i++)
                EMITR(xv[i])
            #pragma unroll
            for (int z = 0; z < 5; z++)   // zero-pad f 219..223 (exactly 224)
                EMITR(0.f)
#undef EMITR
        }

        // ---- stage D tile into LDS: row = (reg&3)+8*(reg>>2)+4*g,
        //      dword = wid*9 + r (channel-major within node row) ----
        if (r < 9) {
            #pragma unroll
            for (int reg = 0; reg < 16; reg++) {
                const int row = (reg & 3) + 8 * (reg >> 2) + 4 * g;
                sOut[row * 40 + wid * 9 + r] = acc[reg];
            }
        }
        __syncthreads();

        // ---- coalesced store: 9 float4 per node = 144B contiguous ----
        for (int q = threadIdx.x; q < 32 * 9; q += 256) {
            const int node = q / 9;
            const int w4 = q % 9;
            if (T * 32 + node < cnt) {
                const float4 v = *reinterpret_cast<const float4*>(&sOut[node * 40 + w4 * 4]);
                float4* gp = reinterpret_cast<float4*>(
                    out + (size_t)sNid[node] * (CC * DD) + blockIdx.x * (CPB * DD));
                gp[w4] = v;
            }
        }
        __syncthreads();

        #pragma unroll
        for (int q = 0; q < 9; q++) xv[q] = xn[q];
        nb_cur = nb_next;
        nb_next = nb_next2;
        T += TS;
    }
}

extern "C" void kernel_launch(void* const* d_in, const int* in_sizes, int n_in,
                              void* d_out, int out_size, void* d_ws, size_t ws_size,
                              hipStream_t stream) {
    const float* x   = (const float*)d_in[0];
    const int* indices = (const int*)d_in[1];
    const float* u3  = (const float*)d_in[2];
    const float* u2  = (const float*)d_in[3];
    const float* u1  = (const float*)d_in[4];
    const float* w3  = (const float*)d_in[5];
    const float* w2  = (const float*)d_in[6];
    const float* w1  = (const float*)d_in[7];
    float* out = (float*)d_out;

    char* ws = (char*)d_ws;
    float* su3 = (float*)(ws + SU3_OFF);
    float* su2 = (float*)(ws + SU2_OFF);
    int* cursors = (int*)(ws + CUR_OFF);
    int* lists = (int*)(ws + LIST_OFF);
    unsigned* Wg16 = (unsigned*)(ws + WG16_OFF);

    const int symn = F3 * PP3 * 9 + F2 * PP2 * 9 + 16;
    hipLaunchKernelGGL(sym_u_zero_kernel, dim3((symn + 255) / 256), dim3(256), 0, stream,
                       u3, u2, su3, su2, cursors);
    hipLaunchKernelGGL(bucket_kernel, dim3((NN + 255) / 256), dim3(256), 0, stream,
                       indices, cursors, lists);
    hipLaunchKernelGGL(wprep16_kernel, dim3(CC, EE), dim3(256), 0, stream,
                       su3, su2, u1, w3, w2, w1, Wg16);
    hipLaunchKernelGGL(symcon_reg32_kernel, dim3(CC / CPB, EE, TS), dim3(256), 0, stream,
                       x, (const unsigned short*)Wg16, cursors, lists, out);
}